// Round 10
// baseline (214.155 us; speedup 1.0000x reference)
//
#include <hip/hip_runtime.h>
#include <hip/hip_bf16.h>

#define Bc 2
#define Hc 32
#define N1c 1024
#define Nc 1023
#define BLOCK 256
#define PLANE (N1c * N1c)
#define JT 128    // j's per tile (2 threads cooperate per j: h-halves)
#define NT 8      // tiles per row
#define LDSW 40   // 80 B LDS rows (R2/R7/R9-proven layout)

typedef __attribute__((ext_vector_type(8))) short bf16x8;
typedef __attribute__((ext_vector_type(4))) float f32x4;

__device__ __forceinline__ unsigned short f2bf(float a) {
    unsigned ua = __float_as_uint(a);
    ua = (ua + 0x7fffu + ((ua >> 16) & 1u)) >> 16;
    return (unsigned short)ua;
}
__device__ __forceinline__ float bflo(unsigned d) { return __uint_as_float(d << 16); }
__device__ __forceinline__ float bfhi(unsigned d) { return __uint_as_float(d & 0xffff0000u); }

__global__ __launch_bounds__(BLOCK, 5) void se3_head_kernel(
    const float* __restrict__ x,    // [B,N,3]
    const float* __restrict__ qk,   // [B,H,N1,N1]
    const float* __restrict__ W1,   // [H,H]
    const float* __restrict__ b1,   // [H]
    const float* __restrict__ W2,   // [1,H]
    const float* __restrict__ b2,   // [1]
    float* __restrict__ out)        // [B,N,3]
{
    __shared__ unsigned short qs[2][JT][LDSW];  // 20480 B: [j''][h] bf16 tile
    __shared__ unsigned xsb[1536];              // 6144 B: bf16 xrow[j'][3]; xrow[0]=0
    __shared__ float red[4][4];

    const int bi   = blockIdx.x;
    const int b    = bi / Nc;
    const int i    = bi % Nc;
    const int t    = threadIdx.x;
    const int w    = t >> 6;
    const int lane = t & 63;
    const int jl   = lane & 15;   // A-row (j'' within 16) / C-col (g)
    const int lk   = lane >> 4;   // k-chunk / C-row-quad
    const int jt   = t & 127;     // staged j'' within tile
    const int hh   = t >> 7;      // h-half owned at load/stage time (0 or 1)

    const float* qk_row = qk + (size_t)b * Hc * PLANE + (size_t)(i + 1) * N1c;
    const float* xb     = x + (size_t)b * Nc * 3;

    // ---- stage bf16 x once: rows 4t..4t+3, xrow[j'] = x[j'-1], xrow[0]=0 ----
    {
        float v[12];
        #pragma unroll
        for (int e = 0; e < 12; ++e) {
            const int gi = 12 * t - 3 + e;
            v[e] = (gi >= 0) ? xb[gi] : 0.f;
        }
        unsigned d[6];
        #pragma unroll
        for (int p = 0; p < 6; ++p) {
            __hip_bfloat162 h2 = __float22bfloat162_rn(make_float2(v[2*p], v[2*p+1]));
            d[p] = *reinterpret_cast<unsigned*>(&h2);
        }
        *reinterpret_cast<uint2*>(&xsb[t*6 + 0]) = make_uint2(d[0], d[1]);
        *reinterpret_cast<uint2*>(&xsb[t*6 + 2]) = make_uint2(d[2], d[3]);
        *reinterpret_cast<uint2*>(&xsb[t*6 + 4]) = make_uint2(d[4], d[5]);
    }

    // ---- per-lane constants (R7/R9-verified geometry + numerics) ----
    bf16x8 B0, B1;   // B[k=h=lk*8+e][col=g=jl] = W1[g][h], cols g and g+16
    #pragma unroll
    for (int e = 0; e < 8; ++e) {
        ((unsigned short*)&B0)[e] = f2bf(W1[jl * Hc + lk*8 + e]);
        ((unsigned short*)&B1)[e] = f2bf(W1[(jl + 16) * Hc + lk*8 + e]);
    }
    const float w2a = W2[jl], w2b = W2[jl + 16];
    const float bb0 = b1[jl], bb1 = b1[jl + 16];
    const f32x4 cb0 = {bb0, bb0, bb0, bb0};
    const f32x4 cb1 = {bb1, bb1, bb1, bb1};
    const float b2s = b2[0] * (1.0f / 16.0f);

    float S = 0.f, T0 = 0.f, T1 = 0.f, T2 = 0.f;
    float rA[16], rB[16];   // half register sets (R9-proven)

    const float* qbase = qk_row + jt + (size_t)(hh * 16) * PLANE;
    auto L = [&](float (&r)[16], int k) {
        const float* p = qbase + k * JT;
        #pragma unroll
        for (int h = 0; h < 16; ++h)
            r[h] = p[(size_t)h * PLANE];
    };

    auto STAGE = [&](const float (&r)[16], int buf) {
        unsigned short* dst = &qs[buf][jt][hh * 16];
        #pragma unroll
        for (int q4 = 0; q4 < 2; ++q4) {
            unsigned pk[4];
            #pragma unroll
            for (int e = 0; e < 4; ++e) {
                __hip_bfloat162 h2 = __float22bfloat162_rn(
                    make_float2(r[q4*8 + 2*e], r[q4*8 + 2*e + 1]));
                pk[e] = *reinterpret_cast<unsigned*>(&h2);
            }
            *reinterpret_cast<uint4*>(dst + q4*8) =
                make_uint4(pk[0], pk[1], pk[2], pk[3]);
        }
    };

    auto COMP = [&](int k, int buf) {
        #pragma unroll
        for (int m = 0; m < 2; ++m) {
            const int row = w * 32 + m * 16;             // wave-owned rows (of 128)
            bf16x8 A = *reinterpret_cast<const bf16x8*>(&qs[buf][row + jl][lk*8]);
            f32x4 c0 = __builtin_amdgcn_mfma_f32_16x16x32_bf16(A, B0, cb0, 0, 0, 0);
            f32x4 c1 = __builtin_amdgcn_mfma_f32_16x16x32_bf16(A, B1, cb1, 0, 0, 0);
            const int jb = k * JT + row + lk * 4;        // this lane's 4 j' (jb%4==0)
            const unsigned* hp = &xsb[jb + (jb >> 1)];   // uint index = 3*jb/2
            const uint2 u01 = *reinterpret_cast<const uint2*>(hp);
            const uint2 u23 = *reinterpret_cast<const uint2*>(hp + 2);
            const uint2 u45 = *reinterpret_cast<const uint2*>(hp + 4);
            const float xj[4][3] = {
                {bflo(u01.x), bfhi(u01.x), bflo(u01.y)},
                {bfhi(u01.y), bflo(u23.x), bfhi(u23.x)},
                {bflo(u23.y), bfhi(u23.y), bflo(u45.x)},
                {bfhi(u45.x), bflo(u45.y), bfhi(u45.y)}};
            #pragma unroll
            for (int r = 0; r < 4; ++r) {
                float cp = fmaf(fmaxf(c0[r], 0.f), w2a,
                             fmaf(fmaxf(c1[r], 0.f), w2b, b2s));
                if (k == 0 && m == 0)                    // only j'==0 invalid
                    cp = (jb + r == 0) ? 0.f : cp;
                S += cp;
                T0 = fmaf(xj[r][0], cp, T0);
                T1 = fmaf(xj[r][1], cp, T1);
                T2 = fmaf(xj[r][2], cp, T2);
            }
        }
    };

    // ---- pipeline: 1 barrier/tile; loads-in-flight never reach zero ----
    L(rA, 0); L(rB, 1);
    STAGE(rA, 0);
    __syncthreads();            // also publishes xsb

    #pragma unroll
    for (int k = 0; k < NT; ++k) {
        const int buf = k & 1;
        if (k + 2 < NT) {                       // issue tile-(k+2) loads first
            if (buf == 0) L(rA, k + 2); else L(rB, k + 2);
        }
        COMP(k, buf);
        if (k + 1 < NT) {
            if (buf == 0) STAGE(rB, 1); else STAGE(rA, 0);
            __syncthreads();
        }
    }

    // ---- block reduction ----
    #pragma unroll
    for (int off = 32; off > 0; off >>= 1) {
        S  += __shfl_down(S,  off);
        T0 += __shfl_down(T0, off);
        T1 += __shfl_down(T1, off);
        T2 += __shfl_down(T2, off);
    }
    if (lane == 0) { red[w][0] = S; red[w][1] = T0; red[w][2] = T1; red[w][3] = T2; }
    __syncthreads();

    if (t == 0) {
        float s = 0.f, u0 = 0.f, u1 = 0.f, u2 = 0.f;
        #pragma unroll
        for (int q = 0; q < 4; ++q) {
            s += red[q][0]; u0 += red[q][1]; u1 += red[q][2]; u2 += red[q][3];
        }
        const float xi0 = xb[i*3], xi1 = xb[i*3+1], xi2 = xb[i*3+2];  // exact fp32
        out[(b*Nc + i)*3 + 0] = fmaf(xi0, s, xi0) - u0;
        out[(b*Nc + i)*3 + 1] = fmaf(xi1, s, xi1) - u1;
        out[(b*Nc + i)*3 + 2] = fmaf(xi2, s, xi2) - u2;
    }
}

extern "C" void kernel_launch(void* const* d_in, const int* in_sizes, int n_in,
                              void* d_out, int out_size, void* d_ws, size_t ws_size,
                              hipStream_t stream) {
    const float* x  = (const float*)d_in[0];
    const float* qk = (const float*)d_in[1];
    const float* W1 = (const float*)d_in[2];
    const float* b1 = (const float*)d_in[3];
    const float* W2 = (const float*)d_in[4];
    const float* b2 = (const float*)d_in[5];
    float* out = (float*)d_out;

    se3_head_kernel<<<dim3(Bc * Nc), dim3(BLOCK), 0, stream>>>(
        x, qk, W1, b1, W2, b2, out);
}

// Round 11
// 48.458 us; speedup vs baseline: 4.4194x; 4.4194x over previous
//
#include <hip/hip_runtime.h>
#include <hip/hip_bf16.h>

#define Bc 2
#define Hc 32
#define N1c 1024
#define Nc 1023
#define BLOCK 256
#define PLANE (N1c * N1c)
#define JT 128    // j's per tile (2 threads cooperate per j: h-halves)
#define NT 8      // tiles per row
#define LDSW 40   // 80 B LDS rows (R2/R7/R9-proven layout)

typedef __attribute__((ext_vector_type(8))) short bf16x8;
typedef __attribute__((ext_vector_type(4))) float f32x4;

__device__ __forceinline__ unsigned short f2bf(float a) {
    unsigned ua = __float_as_uint(a);
    ua = (ua + 0x7fffu + ((ua >> 16) & 1u)) >> 16;
    return (unsigned short)ua;
}

__global__ __launch_bounds__(BLOCK, 4) void se3_head_kernel(
    const float* __restrict__ x,    // [B,N,3]
    const float* __restrict__ qk,   // [B,H,N1,N1]
    const float* __restrict__ W1,   // [H,H]
    const float* __restrict__ b1,   // [H]
    const float* __restrict__ W2,   // [1,H]
    const float* __restrict__ b2,   // [1]
    float* __restrict__ out)        // [B,N,3]
{
    __shared__ unsigned short qs[2][JT][LDSW];  // 20480 B: [j''][h] bf16 tile
    __shared__ float xs[N1c][3];                // xs[j'] = x[j'-1]; xs[0]=0 (12 KB)
    __shared__ float red[4][4];

    const int bi   = blockIdx.x;
    const int b    = bi / Nc;
    const int i    = bi % Nc;
    const int t    = threadIdx.x;
    const int w    = t >> 6;
    const int lane = t & 63;
    const int jl   = lane & 15;   // A-row (j'' within 16) / C-col (g)
    const int lk   = lane >> 4;   // k-chunk / C-row-quad
    const int jt   = t & 127;     // staged j'' within tile
    const int hh   = t >> 7;      // h-half owned at load/stage time (0 or 1)

    const float* qk_row = qk + (size_t)b * Hc * PLANE + (size_t)(i + 1) * N1c;
    const float* xb     = x + (size_t)b * Nc * 3;

    // ---- stage x once: xs[j'] = x[j'-1], xs[0] = 0 (exact f32) ----
    for (int rr = t; rr < N1c; rr += BLOCK) {
        float v0 = 0.f, v1 = 0.f, v2 = 0.f;
        if (rr >= 1) { v0 = xb[(rr-1)*3]; v1 = xb[(rr-1)*3+1]; v2 = xb[(rr-1)*3+2]; }
        xs[rr][0] = v0; xs[rr][1] = v1; xs[rr][2] = v2;
    }

    // ---- per-lane constants (R7-verified geometry + numerics) ----
    bf16x8 B0, B1;   // B[k=h=lk*8+e][col=g=jl] = W1[g][h], cols g and g+16
    #pragma unroll
    for (int e = 0; e < 8; ++e) {
        ((unsigned short*)&B0)[e] = f2bf(W1[jl * Hc + lk*8 + e]);
        ((unsigned short*)&B1)[e] = f2bf(W1[(jl + 16) * Hc + lk*8 + e]);
    }
    const float w2a = W2[jl], w2b = W2[jl + 16];
    const float bb0 = b1[jl], bb1 = b1[jl + 16];
    const f32x4 cb0 = {bb0, bb0, bb0, bb0};
    const f32x4 cb1 = {bb1, bb1, bb1, bb1};
    const float b2s = b2[0] * (1.0f / 16.0f);

    float S = 0.f, T0 = 0.f, T1 = 0.f, T2 = 0.f;
    float rA[16], rB[16];   // HALF register sets: 2 threads per j (h-halves)

    // 16 coalesced streams per thread: uniform per-h base, lane voffset = j''
    const float* qbase = qk_row + jt + (size_t)(hh * 16) * PLANE;
    auto L = [&](float (&r)[16], int k) {
        const float* p = qbase + k * JT;
        #pragma unroll
        for (int h = 0; h < 16; ++h)
            r[h] = p[(size_t)h * PLANE];
    };

    // pack 16 floats -> 8 bf16x2 dwords (v_cvt_pk_bf16_f32), 2x ds_write_b128
    auto STAGE = [&](const float (&r)[16], int buf) {
        unsigned short* dst = &qs[buf][jt][hh * 16];
        #pragma unroll
        for (int q4 = 0; q4 < 2; ++q4) {
            unsigned pk[4];
            #pragma unroll
            for (int e = 0; e < 4; ++e) {
                __hip_bfloat162 h2 = __float22bfloat162_rn(
                    make_float2(r[q4*8 + 2*e], r[q4*8 + 2*e + 1]));
                pk[e] = *reinterpret_cast<unsigned*>(&h2);
            }
            *reinterpret_cast<uint4*>(dst + q4*8) =
                make_uint4(pk[0], pk[1], pk[2], pk[3]);
        }
    };

    auto COMP = [&](int k, int buf) {
        #pragma unroll
        for (int m = 0; m < 2; ++m) {
            const int row = w * 32 + m * 16;             // wave-owned rows (of 128)
            bf16x8 A = *reinterpret_cast<const bf16x8*>(&qs[buf][row + jl][lk*8]);
            f32x4 c0 = __builtin_amdgcn_mfma_f32_16x16x32_bf16(A, B0, cb0, 0, 0, 0);
            f32x4 c1 = __builtin_amdgcn_mfma_f32_16x16x32_bf16(A, B1, cb1, 0, 0, 0);
            const int jb = k * JT + row + lk * 4;        // this lane's 4 j'
            const float* xp = &xs[jb][0];                // 16B-aligned (jb%4==0)
            f32x4 xA = *reinterpret_cast<const f32x4*>(xp);
            f32x4 xB = *reinterpret_cast<const f32x4*>(xp + 4);
            f32x4 xC = *reinterpret_cast<const f32x4*>(xp + 8);
            const float xj[4][3] = {{xA.x, xA.y, xA.z}, {xA.w, xB.x, xB.y},
                                    {xB.z, xB.w, xC.x}, {xC.y, xC.z, xC.w}};
            #pragma unroll
            for (int r = 0; r < 4; ++r) {
                float cp = fmaf(fmaxf(c0[r], 0.f), w2a,
                             fmaf(fmaxf(c1[r], 0.f), w2b, b2s));
                if (k == 0 && m == 0)                    // only j'==0 invalid
                    cp = (jb + r == 0) ? 0.f : cp;
                S += cp;
                T0 = fmaf(xj[r][0], cp, T0);
                T1 = fmaf(xj[r][1], cp, T1);
                T2 = fmaf(xj[r][2], cp, T2);
            }
        }
    };

    // ---- pipeline: 1 barrier/tile; loads-in-flight never reach zero ----
    L(rA, 0); L(rB, 1);
    STAGE(rA, 0);
    __syncthreads();            // also publishes xs

    #pragma unroll
    for (int k = 0; k < NT; ++k) {
        const int buf = k & 1;
        if (k + 2 < NT) {                       // issue tile-(k+2) loads first
            if (buf == 0) L(rA, k + 2); else L(rB, k + 2);
        }
        COMP(k, buf);
        if (k + 1 < NT) {
            if (buf == 0) STAGE(rB, 1); else STAGE(rA, 0);
            __syncthreads();
        }
    }

    // ---- block reduction ----
    #pragma unroll
    for (int off = 32; off > 0; off >>= 1) {
        S  += __shfl_down(S,  off);
        T0 += __shfl_down(T0, off);
        T1 += __shfl_down(T1, off);
        T2 += __shfl_down(T2, off);
    }
    if (lane == 0) { red[w][0] = S; red[w][1] = T0; red[w][2] = T1; red[w][3] = T2; }
    __syncthreads();

    if (t == 0) {
        float s = 0.f, u0 = 0.f, u1 = 0.f, u2 = 0.f;
        #pragma unroll
        for (int q = 0; q < 4; ++q) {
            s += red[q][0]; u0 += red[q][1]; u1 += red[q][2]; u2 += red[q][3];
        }
        const float xi0 = xs[i+1][0], xi1 = xs[i+1][1], xi2 = xs[i+1][2];
        out[(b*Nc + i)*3 + 0] = fmaf(xi0, s, xi0) - u0;
        out[(b*Nc + i)*3 + 1] = fmaf(xi1, s, xi1) - u1;
        out[(b*Nc + i)*3 + 2] = fmaf(xi2, s, xi2) - u2;
    }
}

extern "C" void kernel_launch(void* const* d_in, const int* in_sizes, int n_in,
                              void* d_out, int out_size, void* d_ws, size_t ws_size,
                              hipStream_t stream) {
    const float* x  = (const float*)d_in[0];
    const float* qk = (const float*)d_in[1];
    const float* W1 = (const float*)d_in[2];
    const float* b1 = (const float*)d_in[3];
    const float* W2 = (const float*)d_in[4];
    const float* b2 = (const float*)d_in[5];
    float* out = (float*)d_out;

    se3_head_kernel<<<dim3(Bc * Nc), dim3(BLOCK), 0, stream>>>(
        x, qk, W1, b1, W2, b2, out);
}